// Round 1
// 982.724 us; speedup vs baseline: 1.0863x; 1.0863x over previous
//
#include <hip/hip_runtime.h>
#include <stdint.h>

#define TM 128
#define TN 128
#define BK 128

typedef __attribute__((ext_vector_type(4)))  int i32x4;
typedef __attribute__((ext_vector_type(16))) int i32x16;

__device__ __forceinline__ void async16(const void* g, void* l) {
    __builtin_amdgcn_global_load_lds(
        (const __attribute__((address_space(1))) unsigned int*)g,
        (__attribute__((address_space(3))) unsigned int*)l,
        16 /*bytes*/, 0 /*offset*/, 0 /*aux*/);
}

// Pack int32 (one int8 value per int) -> int8 bytes.
// Coalesced both sides: 16 B/lane contiguous reads, 4 B/lane contiguous writes.
__global__ void pack_both(const int4* __restrict__ sx, int* __restrict__ dx, int nx4,
                          const int4* __restrict__ sw, int* __restrict__ dw, int nw4) {
    int idx    = blockIdx.x * blockDim.x + threadIdx.x;
    int stride = gridDim.x * blockDim.x;
    for (int i = idx; i < nx4; i += stride) {
        int4 a = sx[i];
        dx[i] = (a.x & 0xFF) | ((a.y & 0xFF) << 8) | ((a.z & 0xFF) << 16) | (a.w << 24);
    }
    for (int i = idx; i < nw4; i += stride) {
        int4 a = sw[i];
        dw[i] = (a.x & 0xFF) | ((a.y & 0xFF) << 8) | ((a.z & 0xFF) << 16) | (a.w << 24);
    }
}

// 128x128 tile, BK=128, 4 waves, each wave 64x64 via 2x2 of mfma_i32_32x32x32_i8.
// LDS layout: [row 0..127][128 B], 16B chunk index XOR-swizzled by (row&7).
//   Swizzle applied BOTH sides: inverse-swizzled global source for global_load_lds
//   (linear LDS dest), swizzled address on ds_read -> logical data exact.
// A/B frag (32x32x32 i8): lane holds [row/col = lane&31][k-seg = (lane>>5)*16], 16 B.
// C/D: col = lane&31, row = (reg&3) + 8*(reg>>2) + 4*(lane>>5)  (HW-verified layout).
__global__ __launch_bounds__(256, 2) void w8a8_silu_kernel(
    const int8_t* __restrict__ x, const int8_t* __restrict__ w,
    const float* __restrict__ bias, const float* __restrict__ alpha_p,
    float* __restrict__ out, int M, int N, int K, int nbn)
{
    __shared__ int8_t lds_a[TM * BK];   // 16 KB
    __shared__ int8_t lds_b[TN * BK];   // 16 KB

    const int tid  = threadIdx.x;
    const int lane = tid & 63;
    const int wave = tid >> 6;

    // ---- XCD-aware block swizzle: contiguous chunk per XCD, row-major inside ----
    int bid = blockIdx.x;
    const int nwg = gridDim.x;
    if ((nwg & 7) == 0) bid = (bid & 7) * (nwg >> 3) + (bid >> 3);
    const int bm = bid / nbn;
    const int bn = bid - bm * nbn;

    // ---- staging: thread covers row = (tid>>3) + 32*j, one swizzled 16B chunk ----
    // phys slot = tid*16 + j*4096 -> row = (tid>>3)+32j, phys chunk = tid&7.
    // logical chunk stored there = (tid&7) ^ (row&7) = (tid&7) ^ ((tid>>3)&7)  (j-free).
    const int srow  = tid >> 3;                                // 0..31
    const int skoff = (((tid & 7) ^ (srow & 7)) << 4);         // inverse-swizzled source
    const int8_t* gA = x + ((size_t)bm * TM + srow) * K + skoff;
    const int8_t* gB = w + ((size_t)bn * TN + srow) * K + skoff;
    int8_t* lA = lds_a + tid * 16;
    int8_t* lB = lds_b + tid * 16;

    // ---- per-wave output subtile ----
    const int wr  = (wave >> 1) * 64;   // M
    const int wc  = (wave & 1) * 64;    // N
    const int l31 = lane & 31;
    const int q2  = lane >> 5;          // k-half of MFMA, and C/D row offset
    const int xl  = lane & 7;           // == row&7 for all frag rows (wr,t*32 are mult of 8)

    i32x16 acc[2][2] = {};

    for (int k0 = 0; k0 < K; k0 += BK) {
        __syncthreads();                  // prior iter's ds_reads done
#pragma unroll
        for (int j = 0; j < 4; ++j) {
            async16(gA + (size_t)(j * 32) * K + k0, lA + j * 4096);
            async16(gB + (size_t)(j * 32) * K + k0, lB + j * 4096);
        }
        __syncthreads();                  // drains vmcnt -> LDS valid

#pragma unroll
        for (int ks = 0; ks < 4; ++ks) {
            i32x4 af[2], bf[2];
            const int ck = ((ks * 2 + q2) ^ xl) << 4;   // swizzled chunk byte offset
#pragma unroll
            for (int t = 0; t < 2; ++t) {
                af[t] = *(const i32x4*)(lds_a + ((wr + t * 32 + l31) << 7) + ck);
                bf[t] = *(const i32x4*)(lds_b + ((wc + t * 32 + l31) << 7) + ck);
            }
            acc[0][0] = __builtin_amdgcn_mfma_i32_32x32x32_i8(af[0], bf[0], acc[0][0], 0, 0, 0);
            acc[0][1] = __builtin_amdgcn_mfma_i32_32x32x32_i8(af[0], bf[1], acc[0][1], 0, 0, 0);
            acc[1][0] = __builtin_amdgcn_mfma_i32_32x32x32_i8(af[1], bf[0], acc[1][0], 0, 0, 0);
            acc[1][1] = __builtin_amdgcn_mfma_i32_32x32x32_i8(af[1], bf[1], acc[1][1], 0, 0, 0);
        }
    }

    // ---- epilogue: y = alpha*acc + bias; y*sigmoid(y); fp32 store ----
    const float alpha = *alpha_p;
    const int rowb = bm * TM + wr;
    const int colb = bn * TN + wc;
#pragma unroll
    for (int ct = 0; ct < 2; ++ct) {
        const int col = colb + ct * 32 + l31;
        const float bv = bias[col];
#pragma unroll
        for (int rt = 0; rt < 2; ++rt) {
#pragma unroll
            for (int r = 0; r < 16; ++r) {
                const int row = rowb + rt * 32 + (r & 3) + ((r >> 2) << 3) + (q2 << 2);
                float y = fmaf(alpha, (float)acc[rt][ct][r], bv);
                out[(size_t)row * N + col] = y / (1.0f + __expf(-y));
            }
        }
    }
}

extern "C" void kernel_launch(void* const* d_in, const int* in_sizes, int n_in,
                              void* d_out, int out_size, void* d_ws, size_t ws_size,
                              hipStream_t stream) {
    const int*   x32   = (const int*)d_in[0];     // integer inputs arrive as int32
    const int*   w32   = (const int*)d_in[1];
    const float* bias  = (const float*)d_in[2];
    const float* alpha = (const float*)d_in[3];
    float*       out   = (float*)d_out;

    const int N = in_sizes[2];             // 11008
    const int K = in_sizes[1] / N;         // 4096
    const int M = in_sizes[0] / K;         // 8192

    // pack into workspace: [x8 (M*K)] [w8 (N*K)]
    int8_t* x8 = (int8_t*)d_ws;
    int8_t* w8 = x8 + (size_t)M * K;

    const int nx4 = (int)(((size_t)M * K) / 4);
    const int nw4 = (int)(((size_t)N * K) / 4);
    pack_both<<<2048, 256, 0, stream>>>((const int4*)x32, (int*)x8, nx4,
                                        (const int4*)w32, (int*)w8, nw4);

    const int nbm = M / TM, nbn = N / TN;  // 64, 86 -> 5504 blocks (divisible by 8)
    w8a8_silu_kernel<<<nbm * nbn, 256, 0, stream>>>(x8, w8, bias, alpha, out, M, N, K, nbn);
}